// Round 6
// baseline (2973.303 us; speedup 1.0000x reference)
//
#include <hip/hip_runtime.h>
#include <hip/hip_bf16.h>
#include <math.h>

#define NUM_B 2
#define SEQ_T 2048
#define DIM_D 1024
#define NH 16
#define DH 64
#define KDIM 1024
#define KSEL 8

__device__ __forceinline__ float bf2f(unsigned int u) {
  union { unsigned int i; float f; } v; v.i = u << 16; return v.f;
}

// QKV projection: C[4096 x 3072] = x[4096 x 1024] * wqkv[3072 x 1024]^T.
// fp32 inputs, FP64 accumulation (top-k selection downstream is sensitive to
// score-level accumulation error vs the numpy reference; fp64 makes our Q,K
// near-exact so disagreement collapses to the reference's own rounding).
// Q,K stored fp32 (matches reference's fp32 qkv materialization), V bf16.
// Layout (B,H,T,DH). Tile 64x64, BK=32, 256 threads, 4x4 micro-tile.
__global__ __launch_bounds__(256) void gemm_qkv(
    const float* __restrict__ A, const float* __restrict__ Bm,
    float* __restrict__ qbuf, float* __restrict__ kbuf,
    unsigned short* __restrict__ vbuf) {
  __shared__ __align__(16) float As[32][64];
  __shared__ __align__(16) float Bs[32][64];
  const int tid = threadIdx.x;
  const int row0 = blockIdx.y * 64;
  const int col0 = blockIdx.x * 64;
  const int lrow = tid >> 2;      // 0..63
  const int lk = (tid & 3) << 3;  // 0,8,16,24
  const int tx = tid & 15, ty = tid >> 4;
  const float* ap = A + (size_t)(row0 + lrow) * KDIM + lk;
  const float* bp = Bm + (size_t)(col0 + lrow) * KDIM + lk;
  double c[4][4] = {{0.0, 0.0, 0.0, 0.0}};
  for (int k0 = 0; k0 < KDIM; k0 += 32) {
    const float4 a0 = *(const float4*)(ap + k0);
    const float4 a1 = *(const float4*)(ap + k0 + 4);
    const float4 b0 = *(const float4*)(bp + k0);
    const float4 b1 = *(const float4*)(bp + k0 + 4);
    float* as = &As[lk][lrow];
    float* bs = &Bs[lk][lrow];
    as[0 * 64] = a0.x; as[1 * 64] = a0.y; as[2 * 64] = a0.z; as[3 * 64] = a0.w;
    as[4 * 64] = a1.x; as[5 * 64] = a1.y; as[6 * 64] = a1.z; as[7 * 64] = a1.w;
    bs[0 * 64] = b0.x; bs[1 * 64] = b0.y; bs[2 * 64] = b0.z; bs[3 * 64] = b0.w;
    bs[4 * 64] = b1.x; bs[5 * 64] = b1.y; bs[6 * 64] = b1.z; bs[7 * 64] = b1.w;
    __syncthreads();
#pragma unroll
    for (int kk = 0; kk < 32; ++kk) {
      const float4 a = *(const float4*)&As[kk][ty << 2];
      const float4 b = *(const float4*)&Bs[kk][tx << 2];
      const double ax = a.x, ay = a.y, az = a.z, aw = a.w;
      const double bx = b.x, by = b.y, bz = b.z, bw = b.w;
      c[0][0] = fma(ax, bx, c[0][0]);
      c[0][1] = fma(ax, by, c[0][1]);
      c[0][2] = fma(ax, bz, c[0][2]);
      c[0][3] = fma(ax, bw, c[0][3]);
      c[1][0] = fma(ay, bx, c[1][0]);
      c[1][1] = fma(ay, by, c[1][1]);
      c[1][2] = fma(ay, bz, c[1][2]);
      c[1][3] = fma(ay, bw, c[1][3]);
      c[2][0] = fma(az, bx, c[2][0]);
      c[2][1] = fma(az, by, c[2][1]);
      c[2][2] = fma(az, bz, c[2][2]);
      c[2][3] = fma(az, bw, c[2][3]);
      c[3][0] = fma(aw, bx, c[3][0]);
      c[3][1] = fma(aw, by, c[3][1]);
      c[3][2] = fma(aw, bz, c[3][2]);
      c[3][3] = fma(aw, bw, c[3][3]);
    }
    __syncthreads();
  }
  const int qi = col0 >> 10;            // 0=q 1=k 2=v
  const int head = (col0 & 1023) >> 6;  // 0..15
  const int bb = row0 >> 11;
  const int t0 = row0 & 2047;
  const size_t base = (size_t)(bb * NH + head) * SEQ_T * DH;
  if (qi == 2) {
    unsigned short* dst = vbuf + base;
#pragma unroll
    for (int i = 0; i < 4; ++i)
#pragma unroll
      for (int j = 0; j < 4; ++j) {
        __hip_bfloat16 h = __float2bfloat16((float)c[i][j]);
        dst[(size_t)(t0 + ty * 4 + i) * DH + (tx * 4 + j)] = *(unsigned short*)&h;
      }
  } else {
    float* dst = ((qi == 0) ? qbuf : kbuf) + base;
#pragma unroll
    for (int i = 0; i < 4; ++i)
#pragma unroll
      for (int j = 0; j < 4; ++j)
        dst[(size_t)(t0 + ty * 4 + i) * DH + (tx * 4 + j)] = (float)c[i][j];
  }
}

// Output projection: out[4096 x 1024] = ctx(bf16)[4096 x 1024] * wout^T(fp32).
// fp32 accumulate, fp32 output.
__global__ __launch_bounds__(256) void gemm_out(
    const unsigned short* __restrict__ A, const float* __restrict__ Bm,
    float* __restrict__ obuf) {
  __shared__ __align__(16) float As[32][64];
  __shared__ __align__(16) float Bs[32][64];
  const int tid = threadIdx.x;
  const int row0 = blockIdx.y * 64;
  const int col0 = blockIdx.x * 64;
  const int lrow = tid >> 2;
  const int lk = (tid & 3) << 3;
  const int tx = tid & 15, ty = tid >> 4;
  const unsigned short* ap = A + (size_t)(row0 + lrow) * KDIM + lk;
  const float* bp = Bm + (size_t)(col0 + lrow) * KDIM + lk;
  float c[4][4] = {{0.f, 0.f, 0.f, 0.f}};
  for (int k0 = 0; k0 < KDIM; k0 += 32) {
    const uint4 u = *(const uint4*)(ap + k0);
    const float4 b0 = *(const float4*)(bp + k0);
    const float4 b1 = *(const float4*)(bp + k0 + 4);
    float* as = &As[lk][lrow];
    float* bs = &Bs[lk][lrow];
    as[0 * 64] = bf2f(u.x & 0xffffu); as[1 * 64] = bf2f(u.x >> 16);
    as[2 * 64] = bf2f(u.y & 0xffffu); as[3 * 64] = bf2f(u.y >> 16);
    as[4 * 64] = bf2f(u.z & 0xffffu); as[5 * 64] = bf2f(u.z >> 16);
    as[6 * 64] = bf2f(u.w & 0xffffu); as[7 * 64] = bf2f(u.w >> 16);
    bs[0 * 64] = b0.x; bs[1 * 64] = b0.y; bs[2 * 64] = b0.z; bs[3 * 64] = b0.w;
    bs[4 * 64] = b1.x; bs[5 * 64] = b1.y; bs[6 * 64] = b1.z; bs[7 * 64] = b1.w;
    __syncthreads();
#pragma unroll
    for (int kk = 0; kk < 32; ++kk) {
      const float4 a = *(const float4*)&As[kk][ty << 2];
      const float4 b = *(const float4*)&Bs[kk][tx << 2];
      c[0][0] = fmaf(a.x, b.x, c[0][0]);
      c[0][1] = fmaf(a.x, b.y, c[0][1]);
      c[0][2] = fmaf(a.x, b.z, c[0][2]);
      c[0][3] = fmaf(a.x, b.w, c[0][3]);
      c[1][0] = fmaf(a.y, b.x, c[1][0]);
      c[1][1] = fmaf(a.y, b.y, c[1][1]);
      c[1][2] = fmaf(a.y, b.z, c[1][2]);
      c[1][3] = fmaf(a.y, b.w, c[1][3]);
      c[2][0] = fmaf(a.z, b.x, c[2][0]);
      c[2][1] = fmaf(a.z, b.y, c[2][1]);
      c[2][2] = fmaf(a.z, b.z, c[2][2]);
      c[2][3] = fmaf(a.z, b.w, c[2][3]);
      c[3][0] = fmaf(a.w, b.x, c[3][0]);
      c[3][1] = fmaf(a.w, b.y, c[3][1]);
      c[3][2] = fmaf(a.w, b.z, c[3][2]);
      c[3][3] = fmaf(a.w, b.w, c[3][3]);
    }
    __syncthreads();
  }
#pragma unroll
  for (int i = 0; i < 4; ++i)
#pragma unroll
    for (int j = 0; j < 4; ++j)
      obuf[(size_t)(row0 + ty * 4 + i) * DIM_D + (col0 + tx * 4 + j)] = c[i][j];
}

// One block per (b,h,t) query row. Scores: fp64 dot of fp32 q,k, correctly
// rounded to fp32 for selection (reference selects on fp32 scores; fp64
// accumulation kills our accumulation-order error, the round-5 flip source).
__global__ __launch_bounds__(256) void attn_topk(
    const float* __restrict__ q, const float* __restrict__ kmat,
    const unsigned short* __restrict__ v, unsigned short* __restrict__ ctx) {
  __shared__ float qs[DH];
  __shared__ float ss[SEQ_T];
  __shared__ float redv[256];
  __shared__ int redi[256];
  __shared__ float selv[KSEL];
  __shared__ int seli[KSEL];
  __shared__ int lidx[32];
  __shared__ float lw[32];
  __shared__ int cnt;
  __shared__ float Zs;

  const int tid = threadIdx.x;
  const int bid = blockIdx.x;
  const int t = bid & (SEQ_T - 1);
  const int bh = bid >> 11;  // SEQ_T == 2048
  const float* qrow = q + ((size_t)bh * SEQ_T + t) * DH;
  if (tid < DH) qs[tid] = qrow[tid];
  for (int j = tid; j < SEQ_T; j += 256) ss[j] = -INFINITY;
  __syncthreads();

  for (int j = tid; j <= t; j += 256) {
    const float* krow = kmat + ((size_t)bh * SEQ_T + j) * DH;
    double acc = 0.0;
#pragma unroll
    for (int d = 0; d < DH; d += 4) {
      const float4 kv = *(const float4*)(krow + d);
      acc = fma((double)qs[d + 0], (double)kv.x, acc);
      acc = fma((double)qs[d + 1], (double)kv.y, acc);
      acc = fma((double)qs[d + 2], (double)kv.z, acc);
      acc = fma((double)qs[d + 3], (double)kv.w, acc);
    }
    ss[j] = (float)(acc * 0.125);
  }
  __syncthreads();

  const int keff = (t + 1 < KSEL) ? (t + 1) : KSEL;
  for (int it = 0; it < keff; ++it) {
    float lv = -INFINITY;
    int li = -1;
    for (int j = tid; j <= t; j += 256) {
      const float sv = ss[j];
      if (sv > lv) { lv = sv; li = j; }
    }
    redv[tid] = lv;
    redi[tid] = li;
    __syncthreads();
    for (int s = 128; s > 0; s >>= 1) {
      if (tid < s && redv[tid + s] > redv[tid]) {
        redv[tid] = redv[tid + s];
        redi[tid] = redi[tid + s];
      }
      __syncthreads();
    }
    if (tid == 0) {
      selv[it] = redv[0];
      seli[it] = redi[0];
      ss[redi[0]] = -INFINITY;
    }
    __syncthreads();
  }
  const float thresh = selv[keff - 1];
  const float mx = selv[0];
  if (tid == 0) {
    for (int i = 0; i < keff; ++i) ss[seli[i]] = selv[i];  // restore
    cnt = 0;
  }
  __syncthreads();

  // keep = s >= thresh (ties kept, matching reference)
  for (int j = tid; j <= t; j += 256) {
    const float sv = ss[j];
    if (sv >= thresh) {
      const int p = atomicAdd(&cnt, 1);
      if (p < 32) {
        lidx[p] = j;
        lw[p] = expf(sv - mx);
      }
    }
  }
  __syncthreads();
  const int n = (cnt < 32) ? cnt : 32;
  if (tid == 0) {
    float z = 0.f;
    for (int l = 0; l < n; ++l) z += lw[l];
    Zs = z;
  }
  __syncthreads();
  if (tid < DH) {
    float acc = 0.f;
    for (int l = 0; l < n; ++l)
      acc += lw[l] * bf2f((unsigned int)v[((size_t)bh * SEQ_T + lidx[l]) * DH + tid]);
    const int bb = bh >> 4;  // NH == 16
    const int hh = bh & 15;
    __hip_bfloat16 h = __float2bfloat16(acc / Zs);
    ctx[((size_t)bb * SEQ_T + t) * DIM_D + hh * DH + tid] = *(unsigned short*)&h;
  }
}

extern "C" void kernel_launch(void* const* d_in, const int* in_sizes, int n_in,
                              void* d_out, int out_size, void* d_ws,
                              size_t ws_size, hipStream_t stream) {
  (void)out_size; (void)ws_size;
  // Identify inputs by element count (robust to ordering). All fp32
  // (confirmed rounds 2-5: fp32 decode yields correct-magnitude output).
  const float* x = (const float*)d_in[0];
  const float* wqkv = (const float*)d_in[1];
  const float* wout = (const float*)d_in[2];
  for (int i = 0; i < n_in; ++i) {
    if (in_sizes[i] == NUM_B * SEQ_T * DIM_D) x = (const float*)d_in[i];
    else if (in_sizes[i] == 3 * DIM_D * DIM_D) wqkv = (const float*)d_in[i];
    else if (in_sizes[i] == DIM_D * DIM_D) wout = (const float*)d_in[i];
  }
  float* out = (float*)d_out;  // fp32 output (reference returns fp32)

  const size_t qkv_elems = (size_t)NUM_B * NH * SEQ_T * DH;  // 4,194,304
  float* qbuf = (float*)d_ws;
  float* kbuf = qbuf + qkv_elems;
  unsigned short* vbuf = (unsigned short*)(kbuf + qkv_elems);
  unsigned short* ctxb = vbuf + qkv_elems;  // bf16 ctx, (B,T,D)

  gemm_qkv<<<dim3(3 * DIM_D / 64, NUM_B * SEQ_T / 64), 256, 0, stream>>>(
      x, wqkv, qbuf, kbuf, vbuf);
  attn_topk<<<dim3(NUM_B * NH * SEQ_T), 256, 0, stream>>>(qbuf, kbuf, vbuf, ctxb);
  gemm_out<<<dim3(DIM_D / 64, NUM_B * SEQ_T / 64), 256, 0, stream>>>(
      ctxb, wout, out);
}

// Round 7
// 1399.446 us; speedup vs baseline: 2.1246x; 2.1246x over previous
//
#include <hip/hip_runtime.h>
#include <hip/hip_bf16.h>
#include <math.h>
#include <float.h>

#define NUM_B 2
#define SEQ_T 2048
#define DIM_D 1024
#define NH 16
#define DH 64
#define KDIM 1024
#define KSEL 8

__device__ __forceinline__ float bf2f(unsigned int u) {
  union { unsigned int i; float f; } v; v.i = u << 16; return v.f;
}

// QKV projection: C[4096 x 3072] = x[4096 x 1024] * wqkv[3072 x 1024]^T.
// fp32 inputs, FP64 accumulation — DO NOT change op order: downstream top-k
// selection depends on these exact bits (verified passing round 6).
__global__ __launch_bounds__(256) void gemm_qkv(
    const float* __restrict__ A, const float* __restrict__ Bm,
    float* __restrict__ qbuf, float* __restrict__ kbuf,
    unsigned short* __restrict__ vbuf) {
  __shared__ __align__(16) float As[32][64];
  __shared__ __align__(16) float Bs[32][64];
  const int tid = threadIdx.x;
  const int row0 = blockIdx.y * 64;
  const int col0 = blockIdx.x * 64;
  const int lrow = tid >> 2;
  const int lk = (tid & 3) << 3;
  const int tx = tid & 15, ty = tid >> 4;
  const float* ap = A + (size_t)(row0 + lrow) * KDIM + lk;
  const float* bp = Bm + (size_t)(col0 + lrow) * KDIM + lk;
  double c[4][4] = {{0.0, 0.0, 0.0, 0.0}};
  for (int k0 = 0; k0 < KDIM; k0 += 32) {
    const float4 a0 = *(const float4*)(ap + k0);
    const float4 a1 = *(const float4*)(ap + k0 + 4);
    const float4 b0 = *(const float4*)(bp + k0);
    const float4 b1 = *(const float4*)(bp + k0 + 4);
    float* as = &As[lk][lrow];
    float* bs = &Bs[lk][lrow];
    as[0 * 64] = a0.x; as[1 * 64] = a0.y; as[2 * 64] = a0.z; as[3 * 64] = a0.w;
    as[4 * 64] = a1.x; as[5 * 64] = a1.y; as[6 * 64] = a1.z; as[7 * 64] = a1.w;
    bs[0 * 64] = b0.x; bs[1 * 64] = b0.y; bs[2 * 64] = b0.z; bs[3 * 64] = b0.w;
    bs[4 * 64] = b1.x; bs[5 * 64] = b1.y; bs[6 * 64] = b1.z; bs[7 * 64] = b1.w;
    __syncthreads();
#pragma unroll
    for (int kk = 0; kk < 32; ++kk) {
      const float4 a = *(const float4*)&As[kk][ty << 2];
      const float4 b = *(const float4*)&Bs[kk][tx << 2];
      const double ax = a.x, ay = a.y, az = a.z, aw = a.w;
      const double bx = b.x, by = b.y, bz = b.z, bw = b.w;
      c[0][0] = fma(ax, bx, c[0][0]);
      c[0][1] = fma(ax, by, c[0][1]);
      c[0][2] = fma(ax, bz, c[0][2]);
      c[0][3] = fma(ax, bw, c[0][3]);
      c[1][0] = fma(ay, bx, c[1][0]);
      c[1][1] = fma(ay, by, c[1][1]);
      c[1][2] = fma(ay, bz, c[1][2]);
      c[1][3] = fma(ay, bw, c[1][3]);
      c[2][0] = fma(az, bx, c[2][0]);
      c[2][1] = fma(az, by, c[2][1]);
      c[2][2] = fma(az, bz, c[2][2]);
      c[2][3] = fma(az, bw, c[2][3]);
      c[3][0] = fma(aw, bx, c[3][0]);
      c[3][1] = fma(aw, by, c[3][1]);
      c[3][2] = fma(aw, bz, c[3][2]);
      c[3][3] = fma(aw, bw, c[3][3]);
    }
    __syncthreads();
  }
  const int qi = col0 >> 10;
  const int head = (col0 & 1023) >> 6;
  const int bb = row0 >> 11;
  const int t0 = row0 & 2047;
  const size_t base = (size_t)(bb * NH + head) * SEQ_T * DH;
  if (qi == 2) {
    unsigned short* dst = vbuf + base;
#pragma unroll
    for (int i = 0; i < 4; ++i)
#pragma unroll
      for (int j = 0; j < 4; ++j) {
        __hip_bfloat16 h = __float2bfloat16((float)c[i][j]);
        dst[(size_t)(t0 + ty * 4 + i) * DH + (tx * 4 + j)] = *(unsigned short*)&h;
      }
  } else {
    float* dst = ((qi == 0) ? qbuf : kbuf) + base;
#pragma unroll
    for (int i = 0; i < 4; ++i)
#pragma unroll
      for (int j = 0; j < 4; ++j)
        dst[(size_t)(t0 + ty * 4 + i) * DH + (tx * 4 + j)] = (float)c[i][j];
  }
}

// Output projection: out[4096 x 1024] = ctx(bf16) * wout^T(fp32), fp32 out.
__global__ __launch_bounds__(256) void gemm_out(
    const unsigned short* __restrict__ A, const float* __restrict__ Bm,
    float* __restrict__ obuf) {
  __shared__ __align__(16) float As[32][64];
  __shared__ __align__(16) float Bs[32][64];
  const int tid = threadIdx.x;
  const int row0 = blockIdx.y * 64;
  const int col0 = blockIdx.x * 64;
  const int lrow = tid >> 2;
  const int lk = (tid & 3) << 3;
  const int tx = tid & 15, ty = tid >> 4;
  const unsigned short* ap = A + (size_t)(row0 + lrow) * KDIM + lk;
  const float* bp = Bm + (size_t)(col0 + lrow) * KDIM + lk;
  float c[4][4] = {{0.f, 0.f, 0.f, 0.f}};
  for (int k0 = 0; k0 < KDIM; k0 += 32) {
    const uint4 u = *(const uint4*)(ap + k0);
    const float4 b0 = *(const float4*)(bp + k0);
    const float4 b1 = *(const float4*)(bp + k0 + 4);
    float* as = &As[lk][lrow];
    float* bs = &Bs[lk][lrow];
    as[0 * 64] = bf2f(u.x & 0xffffu); as[1 * 64] = bf2f(u.x >> 16);
    as[2 * 64] = bf2f(u.y & 0xffffu); as[3 * 64] = bf2f(u.y >> 16);
    as[4 * 64] = bf2f(u.z & 0xffffu); as[5 * 64] = bf2f(u.z >> 16);
    as[6 * 64] = bf2f(u.w & 0xffffu); as[7 * 64] = bf2f(u.w >> 16);
    bs[0 * 64] = b0.x; bs[1 * 64] = b0.y; bs[2 * 64] = b0.z; bs[3 * 64] = b0.w;
    bs[4 * 64] = b1.x; bs[5 * 64] = b1.y; bs[6 * 64] = b1.z; bs[7 * 64] = b1.w;
    __syncthreads();
#pragma unroll
    for (int kk = 0; kk < 32; ++kk) {
      const float4 a = *(const float4*)&As[kk][ty << 2];
      const float4 b = *(const float4*)&Bs[kk][tx << 2];
      c[0][0] = fmaf(a.x, b.x, c[0][0]);
      c[0][1] = fmaf(a.x, b.y, c[0][1]);
      c[0][2] = fmaf(a.x, b.z, c[0][2]);
      c[0][3] = fmaf(a.x, b.w, c[0][3]);
      c[1][0] = fmaf(a.y, b.x, c[1][0]);
      c[1][1] = fmaf(a.y, b.y, c[1][1]);
      c[1][2] = fmaf(a.y, b.z, c[1][2]);
      c[1][3] = fmaf(a.y, b.w, c[1][3]);
      c[2][0] = fmaf(a.z, b.x, c[2][0]);
      c[2][1] = fmaf(a.z, b.y, c[2][1]);
      c[2][2] = fmaf(a.z, b.z, c[2][2]);
      c[2][3] = fmaf(a.z, b.w, c[2][3]);
      c[3][0] = fmaf(a.w, b.x, c[3][0]);
      c[3][1] = fmaf(a.w, b.y, c[3][1]);
      c[3][2] = fmaf(a.w, b.z, c[3][2]);
      c[3][3] = fmaf(a.w, b.w, c[3][3]);
    }
    __syncthreads();
  }
#pragma unroll
  for (int i = 0; i < 4; ++i)
#pragma unroll
    for (int j = 0; j < 4; ++j)
      obuf[(size_t)(row0 + ty * 4 + i) * DIM_D + (col0 + tx * 4 + j)] = c[i][j];
}

// Attention: 1 wave per q-row, 4 rows (4 waves) per block sharing K tiles in
// LDS. Scores fp64-accumulated (bit-identical to round 6), kept in registers.
// Top-8 via per-lane sorted-8 insert + shfl_xor bitonic butterfly (no LDS
// reductions, no per-iteration barriers). keep = score >= thresh (ties kept).
#define TILE 128
#define KST 68  // LDS row stride (floats); 17*lane mod 32 bijective -> no conflicts
__global__ __launch_bounds__(256) void attn_topk(
    const float* __restrict__ q, const float* __restrict__ kmat,
    const unsigned short* __restrict__ v, unsigned short* __restrict__ ctx) {
  __shared__ __align__(16) float kt[TILE * KST];
  __shared__ float qsh[4][DH];
  const int tid = threadIdx.x;
  const int lane = tid & 63;
  const int w = tid >> 6;  // wave id = row within group
  const int bh = blockIdx.x >> 9;       // 512 row-groups per (b,h)
  const int t0 = (blockIdx.x & 511) << 2;
  const int t = t0 + w;
  const size_t kbase = (size_t)bh * SEQ_T * DH;

  // load q rows (one per wave)
  qsh[w][lane] = q[kbase + (size_t)t * DH + lane];

  float sreg[32];
#pragma unroll
  for (int i = 0; i < 32; ++i) sreg[i] = -FLT_MAX;

  const int ntiles = ((t0 + 3) >> 7) + 1;  // block-uniform

#pragma unroll
  for (int T = 0; T < 16; ++T) {
    if (T < ntiles) {
      // stage TILE keys x 64 dims into LDS (coalesced, 1 float4/thread/iter)
#pragma unroll
      for (int r = 0; r < 8; ++r) {
        const int idx = r * 256 + tid;
        const int key = idx >> 4;         // 0..127
        const int d4 = (idx & 15) << 2;   // 0,4,..,60
        *(float4*)&kt[key * KST + d4] =
            *(const float4*)&kmat[kbase + (size_t)(T * TILE + key) * DH + d4];
      }
      __syncthreads();
#pragma unroll
      for (int r2 = 0; r2 < 2; ++r2) {
        const int key = T * TILE + r2 * 64 + lane;
        if (key <= t) {
          const float* kr = &kt[(r2 * 64 + lane) * KST];
          double acc = 0.0;
#pragma unroll
          for (int c4 = 0; c4 < 16; ++c4) {
            const float4 kv = *(const float4*)(kr + (c4 << 2));
            acc = fma((double)qsh[w][(c4 << 2) + 0], (double)kv.x, acc);
            acc = fma((double)qsh[w][(c4 << 2) + 1], (double)kv.y, acc);
            acc = fma((double)qsh[w][(c4 << 2) + 2], (double)kv.z, acc);
            acc = fma((double)qsh[w][(c4 << 2) + 3], (double)kv.w, acc);
          }
          sreg[2 * T + r2] = (float)(acc * 0.125);
        }
      }
      __syncthreads();
    }
  }

  // per-lane sorted top-8 (descending) over the 32 register scores
  float a[8];
#pragma unroll
  for (int j = 0; j < 8; ++j) a[j] = -FLT_MAX;
#pragma unroll
  for (int i = 0; i < 32; ++i) {
    float s = sreg[i];
#pragma unroll
    for (int j = 0; j < 8; ++j) {
      const float hi = fmaxf(a[j], s);
      s = fminf(a[j], s);
      a[j] = hi;
    }
  }
  // butterfly merge across 64 lanes: 6 rounds of bitonic top-8 merge
#pragma unroll
  for (int xm = 1; xm < 64; xm <<= 1) {
    float m[8];
#pragma unroll
    for (int j = 0; j < 8; ++j) {
      const float pb = __shfl_xor(a[7 - j], xm);  // partner reversed
      m[j] = fmaxf(a[j], pb);
    }
    // bitonic sort (descending) of the 8-element bitonic sequence
#pragma unroll
    for (int d = 4; d >= 1; d >>= 1)
#pragma unroll
      for (int j = 0; j < 8; ++j)
        if ((j & d) == 0 && (j | d) < 8) {
          const float hi = fmaxf(m[j], m[j | d]);
          const float lo = fminf(m[j], m[j | d]);
          m[j] = hi;
          m[j | d] = lo;
        }
#pragma unroll
    for (int j = 0; j < 8; ++j) a[j] = m[j];
  }
  const float thresh = a[7];  // k-eff-th largest (=-FLT_MAX when t+1<8: keep all)
  const float mx = a[0];

  // sparse softmax * V, ascending key order (deterministic)
  float accv = 0.f;
  float Z = 0.f;
#pragma unroll
  for (int i = 0; i < 32; ++i) {
    const int mykey = (i << 6) + lane;
    const bool keep = (mykey <= t) && (sreg[i] >= thresh);
    unsigned long long mask = __ballot(keep);
    while (mask) {
      const int b = __ffsll(mask) - 1;
      mask &= mask - 1;
      const float sv = __shfl(sreg[i], b);
      const float wgt = expf(sv - mx);
      Z += wgt;
      const int key = (i << 6) + b;
      accv = fmaf(wgt, bf2f((unsigned int)v[kbase + (size_t)key * DH + lane]), accv);
    }
  }
  const int bb = bh >> 4;
  const int hh = bh & 15;
  __hip_bfloat16 h = __float2bfloat16(accv / Z);
  ctx[((size_t)bb * SEQ_T + t) * DIM_D + hh * DH + lane] = *(unsigned short*)&h;
}

extern "C" void kernel_launch(void* const* d_in, const int* in_sizes, int n_in,
                              void* d_out, int out_size, void* d_ws,
                              size_t ws_size, hipStream_t stream) {
  (void)out_size; (void)ws_size;
  const float* x = (const float*)d_in[0];
  const float* wqkv = (const float*)d_in[1];
  const float* wout = (const float*)d_in[2];
  for (int i = 0; i < n_in; ++i) {
    if (in_sizes[i] == NUM_B * SEQ_T * DIM_D) x = (const float*)d_in[i];
    else if (in_sizes[i] == 3 * DIM_D * DIM_D) wqkv = (const float*)d_in[i];
    else if (in_sizes[i] == DIM_D * DIM_D) wout = (const float*)d_in[i];
  }
  float* out = (float*)d_out;

  const size_t qkv_elems = (size_t)NUM_B * NH * SEQ_T * DH;
  float* qbuf = (float*)d_ws;
  float* kbuf = qbuf + qkv_elems;
  unsigned short* vbuf = (unsigned short*)(kbuf + qkv_elems);
  unsigned short* ctxb = vbuf + qkv_elems;

  gemm_qkv<<<dim3(3 * DIM_D / 64, NUM_B * SEQ_T / 64), 256, 0, stream>>>(
      x, wqkv, qbuf, kbuf, vbuf);
  attn_topk<<<dim3(NUM_B * NH * (SEQ_T / 4)), 256, 0, stream>>>(qbuf, kbuf,
                                                                vbuf, ctxb);
  gemm_out<<<dim3(DIM_D / 64, NUM_B * SEQ_T / 64), 256, 0, stream>>>(
      ctxb, wout, out);
}

// Round 8
// 1207.753 us; speedup vs baseline: 2.4618x; 1.1587x over previous
//
#include <hip/hip_runtime.h>
#include <hip/hip_bf16.h>
#include <math.h>
#include <float.h>

#define NUM_B 2
#define SEQ_T 2048
#define DIM_D 1024
#define NH 16
#define DH 64
#define KDIM 1024
#define KSEL 8

__device__ __forceinline__ float bf2f(unsigned int u) {
  union { unsigned int i; float f; } v; v.i = u << 16; return v.f;
}

__device__ __forceinline__ double shfl_xor_d(double x, int m) {
  union { double d; int i[2]; } u;
  u.d = x;
  u.i[0] = __shfl_xor(u.i[0], m);
  u.i[1] = __shfl_xor(u.i[1], m);
  return u.d;
}

// Q,K projection (cols 0..2047 of qkv): fp64 accumulation, BIT-IDENTICAL to
// the round-6/7 passing path — top-k selection depends on these exact bits.
__global__ __launch_bounds__(256) void gemm_qk(
    const float* __restrict__ A, const float* __restrict__ Bm,
    float* __restrict__ qbuf, float* __restrict__ kbuf) {
  __shared__ __align__(16) float As[32][64];
  __shared__ __align__(16) float Bs[32][64];
  const int tid = threadIdx.x;
  const int row0 = blockIdx.y * 64;
  const int col0 = blockIdx.x * 64;
  const int lrow = tid >> 2;
  const int lk = (tid & 3) << 3;
  const int tx = tid & 15, ty = tid >> 4;
  const float* ap = A + (size_t)(row0 + lrow) * KDIM + lk;
  const float* bp = Bm + (size_t)(col0 + lrow) * KDIM + lk;
  double c[4][4] = {{0.0, 0.0, 0.0, 0.0}};
  for (int k0 = 0; k0 < KDIM; k0 += 32) {
    const float4 a0 = *(const float4*)(ap + k0);
    const float4 a1 = *(const float4*)(ap + k0 + 4);
    const float4 b0 = *(const float4*)(bp + k0);
    const float4 b1 = *(const float4*)(bp + k0 + 4);
    float* as = &As[lk][lrow];
    float* bs = &Bs[lk][lrow];
    as[0 * 64] = a0.x; as[1 * 64] = a0.y; as[2 * 64] = a0.z; as[3 * 64] = a0.w;
    as[4 * 64] = a1.x; as[5 * 64] = a1.y; as[6 * 64] = a1.z; as[7 * 64] = a1.w;
    bs[0 * 64] = b0.x; bs[1 * 64] = b0.y; bs[2 * 64] = b0.z; bs[3 * 64] = b0.w;
    bs[4 * 64] = b1.x; bs[5 * 64] = b1.y; bs[6 * 64] = b1.z; bs[7 * 64] = b1.w;
    __syncthreads();
#pragma unroll
    for (int kk = 0; kk < 32; ++kk) {
      const float4 a = *(const float4*)&As[kk][ty << 2];
      const float4 b = *(const float4*)&Bs[kk][tx << 2];
      const double ax = a.x, ay = a.y, az = a.z, aw = a.w;
      const double bx = b.x, by = b.y, bz = b.z, bw = b.w;
      c[0][0] = fma(ax, bx, c[0][0]);
      c[0][1] = fma(ax, by, c[0][1]);
      c[0][2] = fma(ax, bz, c[0][2]);
      c[0][3] = fma(ax, bw, c[0][3]);
      c[1][0] = fma(ay, bx, c[1][0]);
      c[1][1] = fma(ay, by, c[1][1]);
      c[1][2] = fma(ay, bz, c[1][2]);
      c[1][3] = fma(ay, bw, c[1][3]);
      c[2][0] = fma(az, bx, c[2][0]);
      c[2][1] = fma(az, by, c[2][1]);
      c[2][2] = fma(az, bz, c[2][2]);
      c[2][3] = fma(az, bw, c[2][3]);
      c[3][0] = fma(aw, bx, c[3][0]);
      c[3][1] = fma(aw, by, c[3][1]);
      c[3][2] = fma(aw, bz, c[3][2]);
      c[3][3] = fma(aw, bw, c[3][3]);
    }
    __syncthreads();
  }
  const int qi = col0 >> 10;            // 0=q 1=k
  const int head = (col0 & 1023) >> 6;
  const int bb = row0 >> 11;
  const int t0 = row0 & 2047;
  const size_t base = (size_t)(bb * NH + head) * SEQ_T * DH;
  float* dst = ((qi == 0) ? qbuf : kbuf) + base;
#pragma unroll
  for (int i = 0; i < 4; ++i)
#pragma unroll
    for (int j = 0; j < 4; ++j)
      dst[(size_t)(t0 + ty * 4 + i) * DH + (tx * 4 + j)] = (float)c[i][j];
}

// V projection (cols 2048..3071): fp32 accumulate (V feeds softmax*V and is
// bf16-rounded; fp32 accumulation error ~1e-5 rel is invisible there).
// Bm passed pre-offset to wqkv + 2048*KDIM.
__global__ __launch_bounds__(256) void gemm_v(
    const float* __restrict__ A, const float* __restrict__ Bm,
    unsigned short* __restrict__ vbuf) {
  __shared__ __align__(16) float As[32][64];
  __shared__ __align__(16) float Bs[32][64];
  const int tid = threadIdx.x;
  const int row0 = blockIdx.y * 64;
  const int col0 = blockIdx.x * 64;
  const int lrow = tid >> 2;
  const int lk = (tid & 3) << 3;
  const int tx = tid & 15, ty = tid >> 4;
  const float* ap = A + (size_t)(row0 + lrow) * KDIM + lk;
  const float* bp = Bm + (size_t)(col0 + lrow) * KDIM + lk;
  float c[4][4] = {{0.f, 0.f, 0.f, 0.f}};
  for (int k0 = 0; k0 < KDIM; k0 += 32) {
    const float4 a0 = *(const float4*)(ap + k0);
    const float4 a1 = *(const float4*)(ap + k0 + 4);
    const float4 b0 = *(const float4*)(bp + k0);
    const float4 b1 = *(const float4*)(bp + k0 + 4);
    float* as = &As[lk][lrow];
    float* bs = &Bs[lk][lrow];
    as[0 * 64] = a0.x; as[1 * 64] = a0.y; as[2 * 64] = a0.z; as[3 * 64] = a0.w;
    as[4 * 64] = a1.x; as[5 * 64] = a1.y; as[6 * 64] = a1.z; as[7 * 64] = a1.w;
    bs[0 * 64] = b0.x; bs[1 * 64] = b0.y; bs[2 * 64] = b0.z; bs[3 * 64] = b0.w;
    bs[4 * 64] = b1.x; bs[5 * 64] = b1.y; bs[6 * 64] = b1.z; bs[7 * 64] = b1.w;
    __syncthreads();
#pragma unroll
    for (int kk = 0; kk < 32; ++kk) {
      const float4 a = *(const float4*)&As[kk][ty << 2];
      const float4 b = *(const float4*)&Bs[kk][tx << 2];
      c[0][0] = fmaf(a.x, b.x, c[0][0]);
      c[0][1] = fmaf(a.x, b.y, c[0][1]);
      c[0][2] = fmaf(a.x, b.z, c[0][2]);
      c[0][3] = fmaf(a.x, b.w, c[0][3]);
      c[1][0] = fmaf(a.y, b.x, c[1][0]);
      c[1][1] = fmaf(a.y, b.y, c[1][1]);
      c[1][2] = fmaf(a.y, b.z, c[1][2]);
      c[1][3] = fmaf(a.y, b.w, c[1][3]);
      c[2][0] = fmaf(a.z, b.x, c[2][0]);
      c[2][1] = fmaf(a.z, b.y, c[2][1]);
      c[2][2] = fmaf(a.z, b.z, c[2][2]);
      c[2][3] = fmaf(a.z, b.w, c[2][3]);
      c[3][0] = fmaf(a.w, b.x, c[3][0]);
      c[3][1] = fmaf(a.w, b.y, c[3][1]);
      c[3][2] = fmaf(a.w, b.z, c[3][2]);
      c[3][3] = fmaf(a.w, b.w, c[3][3]);
    }
    __syncthreads();
  }
  const int head = col0 >> 6;  // col0 in 0..1023 here
  const int bb = row0 >> 11;
  const int t0 = row0 & 2047;
  unsigned short* dst = vbuf + (size_t)(bb * NH + head) * SEQ_T * DH;
#pragma unroll
  for (int i = 0; i < 4; ++i)
#pragma unroll
    for (int j = 0; j < 4; ++j) {
      __hip_bfloat16 h = __float2bfloat16(c[i][j]);
      dst[(size_t)(t0 + ty * 4 + i) * DH + (tx * 4 + j)] = *(unsigned short*)&h;
    }
}

// Attention, candidate-filter scheme. 1 wave/q-row, 4 rows/block, shared K
// tiles in LDS. Scores in fp32 (error <= ~1e-5 post-scale); top-8 in fp32;
// keys with s32 >= a[7]-4e-3 (margin 400x error bound) are re-verified with
// an EXACT fp64 wave-distributed dot so selection + weights are value-
// identical to the round-6 fp64-exact path. keep = s64 >= thr64 (ties kept).
#define TILE 128
#define KST 68
__global__ __launch_bounds__(256) void attn_topk(
    const float* __restrict__ q, const float* __restrict__ kmat,
    const unsigned short* __restrict__ v, unsigned short* __restrict__ ctx) {
  __shared__ __align__(16) float kt[TILE * KST];
  __shared__ __align__(16) float qsh[4][DH];
  __shared__ double csd[4][32];
  __shared__ int cid[4][32];
  const int tid = threadIdx.x;
  const int lane = tid & 63;
  const int w = tid >> 6;
  const int bh = blockIdx.x >> 9;
  const int t0 = (blockIdx.x & 511) << 2;
  const int t = t0 + w;
  const size_t kbase = (size_t)bh * SEQ_T * DH;

  qsh[w][lane] = q[kbase + (size_t)t * DH + lane];  // wave-local, no barrier
  float4 qv[16];
#pragma unroll
  for (int j = 0; j < 16; ++j) qv[j] = *(const float4*)&qsh[w][j << 2];

  float sreg[32];
#pragma unroll
  for (int i = 0; i < 32; ++i) sreg[i] = -FLT_MAX;

  const int ntiles = ((t0 + 3) >> 7) + 1;  // block-uniform

#pragma unroll
  for (int T = 0; T < 16; ++T) {
    if (T < ntiles) {
#pragma unroll
      for (int r = 0; r < 8; ++r) {
        const int idx = r * 256 + tid;
        const int key = idx >> 4;
        const int d4 = (idx & 15) << 2;
        *(float4*)&kt[key * KST + d4] =
            *(const float4*)&kmat[kbase + (size_t)(T * TILE + key) * DH + d4];
      }
      __syncthreads();
#pragma unroll
      for (int r2 = 0; r2 < 2; ++r2) {
        const int key = T * TILE + r2 * 64 + lane;
        if (key <= t) {
          const float* kr = &kt[(r2 * 64 + lane) * KST];
          float acc = 0.f;
#pragma unroll
          for (int c4 = 0; c4 < 16; ++c4) {
            const float4 kv = *(const float4*)(kr + (c4 << 2));
            acc = fmaf(qv[c4].x, kv.x, acc);
            acc = fmaf(qv[c4].y, kv.y, acc);
            acc = fmaf(qv[c4].z, kv.z, acc);
            acc = fmaf(qv[c4].w, kv.w, acc);
          }
          sreg[2 * T + r2] = acc * 0.125f;
        }
      }
      __syncthreads();
    }
  }

  // fp32 per-lane sorted top-8, then 6-round shfl_xor bitonic merge
  float a[8];
#pragma unroll
  for (int j = 0; j < 8; ++j) a[j] = -FLT_MAX;
#pragma unroll
  for (int i = 0; i < 32; ++i) {
    float s = sreg[i];
#pragma unroll
    for (int j = 0; j < 8; ++j) {
      const float hi = fmaxf(a[j], s);
      s = fminf(a[j], s);
      a[j] = hi;
    }
  }
#pragma unroll
  for (int xm = 1; xm < 64; xm <<= 1) {
    float m[8];
#pragma unroll
    for (int j = 0; j < 8; ++j) {
      const float pb = __shfl_xor(a[7 - j], xm);
      m[j] = fmaxf(a[j], pb);
    }
#pragma unroll
    for (int d = 4; d >= 1; d >>= 1)
#pragma unroll
      for (int j = 0; j < 8; ++j)
        if ((j & d) == 0 && (j | d) < 8) {
          const float hi = fmaxf(m[j], m[j | d]);
          const float lo = fminf(m[j], m[j | d]);
          m[j] = hi;
          m[j | d] = lo;
        }
#pragma unroll
    for (int j = 0; j < 8; ++j) a[j] = m[j];
  }

  // candidate pass: exact fp64 re-score of keys near/above fp32 threshold
  const float tc = a[7] - 4e-3f;
  const double qd = (double)qsh[w][lane];
  int ncand = 0;
#pragma unroll
  for (int i = 0; i < 32; ++i) {
    const int mykey = (i << 6) + lane;
    const bool cand = (mykey <= t) && (sreg[i] >= tc);
    unsigned long long mask = __ballot(cand);
    while (mask) {
      const int b = __ffsll(mask) - 1;
      mask &= mask - 1;
      const int key = (i << 6) + b;
      double s = qd * (double)kmat[kbase + (size_t)key * DH + lane];
#pragma unroll
      for (int xm = 1; xm < 64; xm <<= 1) s += shfl_xor_d(s, xm);
      s *= 0.125;
      if (ncand < 32) {
        if (lane == 0) {
          csd[w][ncand] = s;
          cid[w][ncand] = key;
        }
        ncand++;
      }
    }
  }
  const int nc = (ncand < 32) ? ncand : 32;

  // fp64 top-8 over candidates (lane-uniform)
  double a64[8];
#pragma unroll
  for (int j = 0; j < 8; ++j) a64[j] = -DBL_MAX;
  for (int l = 0; l < nc; ++l) {
    double sv = csd[w][l];
#pragma unroll
    for (int j = 0; j < 8; ++j) {
      const double hi = fmax(a64[j], sv);
      sv = fmin(a64[j], sv);
      a64[j] = hi;
    }
  }
  const int keff = (t + 1 < KSEL) ? (t + 1) : KSEL;
  double thr64 = a64[7];
#pragma unroll
  for (int j = 0; j < 8; ++j)
    if (j == keff - 1) thr64 = a64[j];
  const float mxf = (float)a64[0];

  // sparse softmax * V over kept candidates (ascending key order)
  float accv = 0.f, Z = 0.f;
  for (int l = 0; l < nc; ++l) {
    const double s = csd[w][l];
    if (s >= thr64) {
      const float wgt = expf((float)s - mxf);
      Z += wgt;
      accv = fmaf(wgt,
                  bf2f((unsigned int)v[kbase + (size_t)cid[w][l] * DH + lane]),
                  accv);
    }
  }
  const int bb = bh >> 4;
  const int hh = bh & 15;
  __hip_bfloat16 h = __float2bfloat16(accv / Z);
  ctx[((size_t)bb * SEQ_T + t) * DIM_D + hh * DH + lane] = *(unsigned short*)&h;
}

// Output projection: out[4096 x 1024] = ctx(bf16) * wout^T(fp32), fp32 out.
__global__ __launch_bounds__(256) void gemm_out(
    const unsigned short* __restrict__ A, const float* __restrict__ Bm,
    float* __restrict__ obuf) {
  __shared__ __align__(16) float As[32][64];
  __shared__ __align__(16) float Bs[32][64];
  const int tid = threadIdx.x;
  const int row0 = blockIdx.y * 64;
  const int col0 = blockIdx.x * 64;
  const int lrow = tid >> 2;
  const int lk = (tid & 3) << 3;
  const int tx = tid & 15, ty = tid >> 4;
  const unsigned short* ap = A + (size_t)(row0 + lrow) * KDIM + lk;
  const float* bp = Bm + (size_t)(col0 + lrow) * KDIM + lk;
  float c[4][4] = {{0.f, 0.f, 0.f, 0.f}};
  for (int k0 = 0; k0 < KDIM; k0 += 32) {
    const uint4 u = *(const uint4*)(ap + k0);
    const float4 b0 = *(const float4*)(bp + k0);
    const float4 b1 = *(const float4*)(bp + k0 + 4);
    float* as = &As[lk][lrow];
    float* bs = &Bs[lk][lrow];
    as[0 * 64] = bf2f(u.x & 0xffffu); as[1 * 64] = bf2f(u.x >> 16);
    as[2 * 64] = bf2f(u.y & 0xffffu); as[3 * 64] = bf2f(u.y >> 16);
    as[4 * 64] = bf2f(u.z & 0xffffu); as[5 * 64] = bf2f(u.z >> 16);
    as[6 * 64] = bf2f(u.w & 0xffffu); as[7 * 64] = bf2f(u.w >> 16);
    bs[0 * 64] = b0.x; bs[1 * 64] = b0.y; bs[2 * 64] = b0.z; bs[3 * 64] = b0.w;
    bs[4 * 64] = b1.x; bs[5 * 64] = b1.y; bs[6 * 64] = b1.z; bs[7 * 64] = b1.w;
    __syncthreads();
#pragma unroll
    for (int kk = 0; kk < 32; ++kk) {
      const float4 a = *(const float4*)&As[kk][ty << 2];
      const float4 b = *(const float4*)&Bs[kk][tx << 2];
      c[0][0] = fmaf(a.x, b.x, c[0][0]);
      c[0][1] = fmaf(a.x, b.y, c[0][1]);
      c[0][2] = fmaf(a.x, b.z, c[0][2]);
      c[0][3] = fmaf(a.x, b.w, c[0][3]);
      c[1][0] = fmaf(a.y, b.x, c[1][0]);
      c[1][1] = fmaf(a.y, b.y, c[1][1]);
      c[1][2] = fmaf(a.y, b.z, c[1][2]);
      c[1][3] = fmaf(a.y, b.w, c[1][3]);
      c[2][0] = fmaf(a.z, b.x, c[2][0]);
      c[2][1] = fmaf(a.z, b.y, c[2][1]);
      c[2][2] = fmaf(a.z, b.z, c[2][2]);
      c[2][3] = fmaf(a.z, b.w, c[2][3]);
      c[3][0] = fmaf(a.w, b.x, c[3][0]);
      c[3][1] = fmaf(a.w, b.y, c[3][1]);
      c[3][2] = fmaf(a.w, b.z, c[3][2]);
      c[3][3] = fmaf(a.w, b.w, c[3][3]);
    }
    __syncthreads();
  }
#pragma unroll
  for (int i = 0; i < 4; ++i)
#pragma unroll
    for (int j = 0; j < 4; ++j)
      obuf[(size_t)(row0 + ty * 4 + i) * DIM_D + (col0 + tx * 4 + j)] = c[i][j];
}

extern "C" void kernel_launch(void* const* d_in, const int* in_sizes, int n_in,
                              void* d_out, int out_size, void* d_ws,
                              size_t ws_size, hipStream_t stream) {
  (void)out_size; (void)ws_size;
  const float* x = (const float*)d_in[0];
  const float* wqkv = (const float*)d_in[1];
  const float* wout = (const float*)d_in[2];
  for (int i = 0; i < n_in; ++i) {
    if (in_sizes[i] == NUM_B * SEQ_T * DIM_D) x = (const float*)d_in[i];
    else if (in_sizes[i] == 3 * DIM_D * DIM_D) wqkv = (const float*)d_in[i];
    else if (in_sizes[i] == DIM_D * DIM_D) wout = (const float*)d_in[i];
  }
  float* out = (float*)d_out;

  const size_t qkv_elems = (size_t)NUM_B * NH * SEQ_T * DH;
  float* qbuf = (float*)d_ws;
  float* kbuf = qbuf + qkv_elems;
  unsigned short* vbuf = (unsigned short*)(kbuf + qkv_elems);
  unsigned short* ctxb = vbuf + qkv_elems;

  gemm_qk<<<dim3(2 * DIM_D / 64, NUM_B * SEQ_T / 64), 256, 0, stream>>>(
      x, wqkv, qbuf, kbuf);
  gemm_v<<<dim3(DIM_D / 64, NUM_B * SEQ_T / 64), 256, 0, stream>>>(
      x, wqkv + (size_t)2 * DIM_D * KDIM, vbuf);
  attn_topk<<<dim3(NUM_B * NH * (SEQ_T / 4)), 256, 0, stream>>>(qbuf, kbuf,
                                                                vbuf, ctxb);
  gemm_out<<<dim3(DIM_D / 64, NUM_B * SEQ_T / 64), 256, 0, stream>>>(
      ctxb, wout, out);
}